// Round 16
// baseline (98.039 us; speedup 1.0000x reference)
//
#include <hip/hip_runtime.h>
#include <math.h>

#define NN 64      // nodes
#define NF 64      // input features (= K of main GEMM)
#define NE 128     // embed
#define NH 256     // hidden
#define NA 6       // atoms
#define NB 4096    // batch
#define NT (NB*NN) // tokens = 262144

// ---- workspace layout (float offsets) ----
#define OFF_WATTN16 8192u     // 2048 fl (reserved, unused)
#define OFF_BE2    20480u     // 64*256 fp32
#define OFF_BATTN  36864u     // 6 (pad 8)
#define OFF_S      36872u     // 64
#define OFF_WATTNF 36944u     // 2048 fl = 4096 bf16 (GEMM2 A-frag: [j>>3][a16][j&7])
#define OFF_XBF    38992u     // 131072 fl = x bf16 in B-frag order [bt][nf][kk][l][8]
#define OFF_WE2F   170064u    // 2097152 fl = We2 bf16 in A-frag order [n][w][mf][kk][l][8]
#define OFF_ARAW   2267216u   // 2097152 fl = [b][n][8]
// end 4364368 floats = 17.5 MB

typedef __attribute__((ext_vector_type(8))) short short8;
typedef __attribute__((ext_vector_type(4))) float f32x4;
typedef __attribute__((ext_vector_type(4))) unsigned short us4;

static __device__ __forceinline__ unsigned short bf16r(float f) {
    unsigned u = __float_as_uint(f);
    return (unsigned short)((u + 0x7FFFu + ((u >> 16) & 1u)) >> 16);
}
static __device__ __forceinline__ unsigned bfpack(float lo, float hi) {
    return (unsigned)bf16r(lo) | ((unsigned)bf16r(hi) << 16);
}

// ---------------------------------------------------------------- kP (fused prep, 512 thr):
// bx 0..255   : (n = bx>>2, jq = bx&3) We2 GEMM -> frag-order bf16 + be2 fp32
// bx 256..319 : x -> bf16 in B-frag order
// bx 320..323 : Wattn (jt) -> frag layouts; jt==0 also battn + zero S
__global__ __launch_bounds__(512) void kP(
        const float* __restrict__ x, const float* __restrict__ Wemb,
        const float* __restrict__ bemb, const float* __restrict__ adjw,
        const float* __restrict__ W1, const float* __restrict__ b1,
        const float* __restrict__ basis, const float* __restrict__ Wq,
        const float* __restrict__ Wk, const float* __restrict__ W2,
        const float* __restrict__ b2, float* __restrict__ ws) {
    __shared__ float sh[17024];
    const int bx = blockIdx.x, t = threadIdx.x;

    if (bx < 256) {
        // ---- We2 GEMM block: n, j-quarter (64 j x 64 f, K=128) ----
        const int n = bx >> 2, jq = bx & 3;
        float* WmT = sh;              // [128 e][68]  (transposed mix, padded)
        float* W1q = sh + 8704;       // [128 e][64 j]
        float* bm  = sh + 16896;      // [128 e]
        const int r = n >> 3, c = n & 7;
        int ml[4]; int nm = 0;
        if (r > 0) ml[nm++] = n - 8;
        if (r < 7) ml[nm++] = n + 8;
        if (c > 0) ml[nm++] = n - 1;
        if (c < 7) ml[nm++] = n + 1;
        float av[4]; float asum = 0.f;
        for (int d = 0; d < nm; ++d) {
            av[d] = 1.f / (1.f + expf(-adjw[n * NN + ml[d]]));
            asum += av[d];
        }
        const float ainv = 1.f / fmaxf(asum, 1e-6f);
        for (int d = 0; d < nm; ++d) av[d] *= ainv;

        #pragma unroll 4
        for (int i = 0; i < 16; ++i) {              // WmT[e][f]
            int idx = i * 512 + t;
            int f = idx >> 7, e = idx & 127;
            float acc = 0.f;
            for (int d = 0; d < nm; ++d)
                acc = fmaf(av[d], Wemb[(size_t)f * (NN * NE) + ml[d] * NE + e], acc);
            WmT[e * 68 + f] = acc;
        }
        if (t < 128) {
            float accb = 0.f;
            for (int d = 0; d < nm; ++d)
                accb = fmaf(av[d], bemb[ml[d] * NE + t], accb);
            bm[t] = accb;
        }
        #pragma unroll 4
        for (int i = 0; i < 16; ++i) {              // W1q[e][j]
            int idx = i * 512 + t;
            int e = idx >> 6, j6 = idx & 63;
            W1q[e * 64 + j6] = W1[(size_t)e * NH + jq * 64 + j6];
        }
        __syncthreads();

        const int jg = t & 15, fg = t >> 4;         // j-quad, f-pair
        float acc[4][2];
        #pragma unroll
        for (int jj = 0; jj < 4; ++jj) { acc[jj][0] = 0.f; acc[jj][1] = 0.f; }
        float accb[4] = {0.f, 0.f, 0.f, 0.f};
        #pragma unroll 4
        for (int e = 0; e < 128; ++e) {
            float4 w1 = *(const float4*)&W1q[e * 64 + jg * 4];
            float2 wm = *(const float2*)&WmT[e * 68 + fg * 2];
            const float w1v[4] = {w1.x, w1.y, w1.z, w1.w};
            #pragma unroll
            for (int jj = 0; jj < 4; ++jj) {
                acc[jj][0] = fmaf(w1v[jj], wm.x, acc[jj][0]);
                acc[jj][1] = fmaf(w1v[jj], wm.y, acc[jj][1]);
            }
            if (fg == 0) {
                float bb = bm[e];
                #pragma unroll
                for (int jj = 0; jj < 4; ++jj) accb[jj] = fmaf(bb, w1v[jj], accb[jj]);
            }
        }
        // frag-order write: f-pair (e0, e0+1) of chunk (n, jq, mf, kk) lane (hi,lo)
        unsigned short* wf = (unsigned short*)(ws + OFF_WE2F);
        const int mfj = jg >> 2, kk = fg >> 4;
        const int lbase = ((fg >> 2) & 3) * 16, e0 = (fg & 3) * 2;
        const size_t cb = ((((size_t)n * 4 + jq) * 4 + mfj) * 2 + kk) * 64;
        #pragma unroll
        for (int jj = 0; jj < 4; ++jj) {
            int l16 = (jg * 4 + jj) & 15;
            *(unsigned*)(wf + (cb + lbase + l16) * 8 + e0) = bfpack(acc[jj][0], acc[jj][1]);
        }
        if (fg == 0) {
            #pragma unroll
            for (int jj = 0; jj < 4; ++jj) {
                int j = jq * 64 + jg * 4 + jj;
                ws[OFF_BE2 + n * NH + j] = accb[jj] + b1[j];
            }
        }
        return;
    }
    if (bx < 320) {
        // ---- x -> bf16 B-frag order ----
        int g = (bx - 256) * 512 + t;               // 0..32767
        int b = g >> 3, ko = g & 7;
        float4 v0 = ((const float4*)x)[b * 16 + ko * 2];
        float4 v1 = ((const float4*)x)[b * 16 + ko * 2 + 1];
        union { unsigned u[4]; short8 v; } cv;
        cv.u[0] = bfpack(v0.x, v0.y); cv.u[1] = bfpack(v0.z, v0.w);
        cv.u[2] = bfpack(v1.x, v1.y); cv.u[3] = bfpack(v1.z, v1.w);
        int bt = b >> 6, nf = (b >> 4) & 3, kk = ko >> 2, l = (ko & 3) * 16 + (b & 15);
        ((short8*)(ws + OFF_XBF))[(((size_t)bt * 4 + nf) * 2 + kk) * 64 + l] = cv.v;
        return;
    }
    // ---- Wattn blocks: jt = bx-320 handles j = jt*64..+63 ----
    const int jt = bx - 320;
    float* Ks  = sh;            // [6][128]
    float* WqK = sh + 768;      // [128][8] (pad)
    float* W2t = sh + 1792;     // [64][129]
    for (int q = t; q < NA * NE; q += 512) {
        int a = q >> 7, e2 = q & 127;
        float acc = 0.f;
        for (int e = 0; e < NE; ++e) acc = fmaf(basis[a * NE + e], Wk[e * NE + e2], acc);
        Ks[a * NE + e2] = acc;
    }
    __syncthreads();
    for (int q = t; q < NE * NA; q += 512) {
        int e = q / NA, a = q - e * NA;
        float acc = 0.f;
        for (int e2 = 0; e2 < NE; ++e2) acc = fmaf(Wq[e * NE + e2], Ks[a * NE + e2], acc);
        WqK[e * 8 + a] = acc;
    }
    __syncthreads();
    for (int i = 0; i < 16; ++i) {                  // stage W2 rows jt*64..+63
        int idx = i * 512 + t;
        int jr = idx >> 7, e = idx & 127;
        W2t[jr * 129 + e] = W2[(size_t)(jt * 64 + jr) * NE + e];
    }
    __syncthreads();
    const float scale = 1.f / (sqrtf(128.f) + 1e-8f);
    unsigned short* wf16 = (unsigned short*)(ws + OFF_WATTNF);
    if (t < 256) {
        const int jl = t & 63, ag = t >> 6;
        const int j = jt * 64 + jl;
        const int na = (ag < 2) ? 2 : 1;
        for (int ai = 0; ai < na; ++ai) {
            int a = ag + ai * 4;
            float acc = 0.f;
            for (int e = 0; e < NE; ++e)
                acc = fmaf(W2t[jl * 129 + e], WqK[e * 8 + a], acc);
            wf16[((j >> 3) * 16 + a) * 8 + (j & 7)] = bf16r(acc * scale);
        }
        if (ag == 3) wf16[((j >> 3) * 16 + 6) * 8 + (j & 7)] = bf16r(1.0f);  // ones col
        for (int a7 = 7 + ag; a7 < 16; a7 += 4)
            wf16[((j >> 3) * 16 + a7) * 8 + (j & 7)] = 0;
    }
    if (jt == 0) {
        __syncthreads();
        if (t < NA) {
            float acc = 0.f;
            for (int e = 0; e < NE; ++e) acc = fmaf(b2[e], WqK[e * 8 + t], acc);
            ws[OFF_BATTN + t] = acc * scale;
        }
        if (t < 64) ws[OFF_S + t] = 0.f;
    }
}

// ---------------------------------------------------------------- A:
// block = (g, n): afr/wfr/be2s loaded ONCE, loop over 8 bt tiles with register
// prefetch. GEMM1 (MFMA) -> relu+bias -> shuffle GEMM2 (proven path).
// Epilogue v2: red double-buffered, hi<2 writes only, ONE barrier per
// iteration, direct scattered ARAW write.
__global__ __launch_bounds__(256) void kA(float* __restrict__ ws) {
    const int g = blockIdx.x, n = blockIdx.y;     // g: 0..7, each covers 8 bt
    const int t = threadIdx.x, w = t >> 6, l = t & 63, lo = l & 15, hi = l >> 4;
    const int j0 = w * 64;
    __shared__ float be2s[256];
    __shared__ float red[2][4][8][64];            // dbuf x wave x a-row x b

    be2s[t] = ws[OFF_BE2 + n * NH + t];

    const short8* Af = (const short8*)(ws + OFF_WE2F);
    const short8* Bf = (const short8*)(ws + OFF_XBF);
    const short8* Wf = (const short8*)(ws + OFF_WATTNF);
    short8 afr[4][2];
    #pragma unroll
    for (int mf = 0; mf < 4; ++mf)
        #pragma unroll
        for (int kk = 0; kk < 2; ++kk)
            afr[mf][kk] = Af[(((size_t)n * 4 + w) * 4 + mf) * 128 + (size_t)kk * 64 + l];
    short8 wfr8[2];
    #pragma unroll
    for (int kk2 = 0; kk2 < 2; ++kk2)
        wfr8[kk2] = Wf[(size_t)(w * 2 + kk2) * 64 + l];

    f32x4 zero = {0.f, 0.f, 0.f, 0.f};
    short8 bcur[4][2], bnxt[4][2];
    #pragma unroll
    for (int nf = 0; nf < 4; ++nf)
        #pragma unroll
        for (int kk = 0; kk < 2; ++kk)
            bcur[nf][kk] = Bf[(((size_t)(g * 8) * 4 + nf) * 2 + kk) * 64 + l];
    float hsacc = 0.f;
    __syncthreads();   // be2s ready

    for (int it = 0; it < 8; ++it) {
        const int bt = g * 8 + it;
        if (it < 7) {   // prefetch next B tile; lands during GEMM1+epilogue
            #pragma unroll
            for (int nf = 0; nf < 4; ++nf)
                #pragma unroll
                for (int kk = 0; kk < 2; ++kk)
                    bnxt[nf][kk] = Bf[(((size_t)(bt + 1) * 4 + nf) * 2 + kk) * 64 + l];
        }

        f32x4 acc[4][4];
        #pragma unroll
        for (int mf = 0; mf < 4; ++mf)
            #pragma unroll
            for (int nf = 0; nf < 4; ++nf) acc[mf][nf] = zero;
        #pragma unroll
        for (int kk = 0; kk < 2; ++kk)
            #pragma unroll
            for (int mf = 0; mf < 4; ++mf)
                #pragma unroll
                for (int nf = 0; nf < 4; ++nf)
                    acc[mf][nf] = __builtin_amdgcn_mfma_f32_16x16x32_bf16(
                        afr[mf][kk], bcur[nf][kk], acc[mf][nf], 0, 0, 0);

        // GEMM2 per kk2: pack only the two mf's it needs (16 P regs live)
        f32x4 acc2[4];
        #pragma unroll
        for (int nf = 0; nf < 4; ++nf) acc2[nf] = zero;
        #pragma unroll
        for (int kk2 = 0; kk2 < 2; ++kk2) {
            unsigned P2[2][4][2];
            #pragma unroll
            for (int dm = 0; dm < 2; ++dm) {
                const int mf = kk2 * 2 + dm;
                const int jb = j0 + mf * 16 + hi * 4;
                #pragma unroll
                for (int nf = 0; nf < 4; ++nf) {
                    float h0 = fmaxf(acc[mf][nf][0] + be2s[jb + 0], 0.f);
                    float h1 = fmaxf(acc[mf][nf][1] + be2s[jb + 1], 0.f);
                    float h2 = fmaxf(acc[mf][nf][2] + be2s[jb + 2], 0.f);
                    float h3 = fmaxf(acc[mf][nf][3] + be2s[jb + 3], 0.f);
                    P2[dm][nf][0] = bfpack(h0, h1);
                    P2[dm][nf][1] = bfpack(h2, h3);
                }
            }
            #pragma unroll
            for (int nf = 0; nf < 4; ++nf) {
                unsigned bq[4];
                #pragma unroll
                for (int q = 0; q < 4; ++q) {
                    int s = ((hi & 1) * 2 + (q >> 1)) * 16 + lo;
                    unsigned vA = (unsigned)__shfl((int)P2[0][nf][q & 1], s, 64);
                    unsigned vB = (unsigned)__shfl((int)P2[1][nf][q & 1], s, 64);
                    bq[q] = (hi >= 2) ? vB : vA;
                }
                union { unsigned u[4]; short8 v; } cv;
                cv.u[0] = bq[0]; cv.u[1] = bq[1]; cv.u[2] = bq[2]; cv.u[3] = bq[3];
                acc2[nf] = __builtin_amdgcn_mfma_f32_16x16x32_bf16(wfr8[kk2], cv.v, acc2[nf], 0, 0, 0);
            }
        }

        // cross-wave partials: only a-rows 0..7 are live
        if (hi < 2) {
            #pragma unroll
            for (int nf = 0; nf < 4; ++nf)
                #pragma unroll
                for (int i = 0; i < 4; ++i)
                    red[it & 1][w][hi * 4 + i][nf * 16 + lo] = acc2[nf][i];
        }
        __syncthreads();                                   // B1 (only barrier)

        const int rb = t & 63, a0 = t >> 6, a1 = a0 + 4;
        const float (*rd)[8][64] = red[it & 1];
        float v0 = rd[0][a0][rb] + rd[1][a0][rb] + rd[2][a0][rb] + rd[3][a0][rb];
        float v1 = rd[0][a1][rb] + rd[1][a1][rb] + rd[2][a1][rb] + rd[3][a1][rb];
        float* ap = ws + OFF_ARAW + ((size_t)(bt * 64 + rb) * 64 + n) * 8;
        ap[a0] = v0;
        ap[a1] = v1;
        if (a1 == 6) {   // wave 2: ones-column = h row-sums
            float hs = v1;
            #pragma unroll
            for (int m = 1; m < 64; m <<= 1) hs += __shfl_xor(hs, m, 64);
            if (l == 0) hsacc += hs;
        }
        if (it < 7) {
            #pragma unroll
            for (int nf = 0; nf < 4; ++nf)
                #pragma unroll
                for (int kk = 0; kk < 2; ++kk)
                    bcur[nf][kk] = bnxt[nf][kk];
        }
    }

    if (w == 2 && l == 0) atomicAdd(ws + OFF_S + n, hsacc);
}

// ---------------------------------------------------------------- C:
// block = FOUR batch rows (ARAW rows contiguous -> one 8 KB staged read).
// Wave w softmaxes row w (all 256 lanes active, one token each); gate chain
// once per block; 4 x 32 KB contiguous output writes.
__global__ __launch_bounds__(256) void kC(const float* __restrict__ ws,
                                          const float* __restrict__ basis,
                                          const float* __restrict__ mW1, const float* __restrict__ mb1,
                                          const float* __restrict__ mW2, const float* __restrict__ mb2,
                                          const float* __restrict__ gW1, const float* __restrict__ gb1,
                                          const float* __restrict__ gW2, const float* __restrict__ gb2,
                                          float* __restrict__ out) {
    const int b4 = blockIdx.x * 4;
    const int t = threadIdx.x;
    __shared__ float ars[2048];          // 4 rows x [n][8]
    __shared__ float sw[4][64][8];
    __shared__ float bs[6][128];
    __shared__ float csh;
    {
        const float4* src = (const float4*)(ws + OFF_ARAW + (size_t)b4 * 512);
        ((float4*)ars)[t]       = src[t];
        ((float4*)ars)[t + 256] = src[t + 256];
    }
    for (int q = t; q < NA * NE; q += 256) bs[q >> 7][q & 127] = basis[q];
    if (t == 0) {   // scalar gate chain (once per 4 rows)
        float S = 0.f;
        for (int i = 0; i < 64; ++i) S += ws[OFF_S + i];
        float s = S / ((float)NB * NN * NH);
        float accm = mb2[0];
        for (int i = 0; i < 8; ++i) accm += fmaxf(s * mW1[i] + mb1[i], 0.f) * mW2[i];
        float m = 1.f / (1.f + expf(-accm));
        float state = 0.9f * 0.5f + 0.1f * m;
        float c1 = 1.f + 0.1f * (state - 0.5f);
        float sg = c1 * s;
        float accg = gb2[0];
        for (int i = 0; i < 16; ++i) accg += fmaxf(sg * gW1[i] + gb1[i], 0.f) * gW2[i];
        float g = 1.f / (1.f + expf(-accg));
        csh = c1 * g;
    }
    __syncthreads();
    {   // wave w handles row w; lane = token
        const float c = csh;
        const int row = t >> 6, tok = t & 63;
        const float* ar = ars + row * 512 + tok * 8;
        float at[6], mx = -1e30f;
        #pragma unroll
        for (int a = 0; a < 6; ++a) {
            at[a] = fmaf(c, ar[a], ws[OFF_BATTN + a]);
            mx = fmaxf(mx, at[a]);
        }
        float ex[6], ssum = 0.f;
        #pragma unroll
        for (int a = 0; a < 6; ++a) { ex[a] = expf(at[a] - mx); ssum += ex[a]; }
        float inv = 1.f / ssum;
        #pragma unroll
        for (int a = 0; a < 6; ++a) sw[row][tok][a] = ex[a] * inv;
    }
    __syncthreads();
    #pragma unroll
    for (int row = 0; row < 4; ++row) {
        float* op = out + (size_t)(b4 + row) * (NN * NE);
        #pragma unroll
        for (int i = 0; i < 8; ++i) {
            int idx = i * 1024 + t * 4;          // 0..8191
            int n = idx >> 7, e = idx & 127;
            float wv[6];
            #pragma unroll
            for (int a = 0; a < 6; ++a) wv[a] = sw[row][n][a];
            float4 r;
            #pragma unroll
            for (int cc = 0; cc < 4; ++cc) {
                float o = 0.f;
                #pragma unroll
                for (int a = 0; a < 6; ++a) o = fmaf(wv[a], bs[a][e + cc], o);
                ((float*)&r)[cc] = fminf(fmaxf(o, -3.f), 3.f);
            }
            *(float4*)(op + idx) = r;
        }
    }
}

extern "C" void kernel_launch(void* const* d_in, const int* in_sizes, int n_in,
                              void* d_out, int out_size, void* d_ws, size_t ws_size,
                              hipStream_t stream) {
    const float* x     = (const float*)d_in[0];
    const float* Wemb  = (const float*)d_in[1];
    const float* bemb  = (const float*)d_in[2];
    const float* adjw  = (const float*)d_in[3];
    const float* W1    = (const float*)d_in[4];
    const float* b1    = (const float*)d_in[5];
    const float* W2    = (const float*)d_in[6];
    const float* b2    = (const float*)d_in[7];
    const float* basis = (const float*)d_in[8];
    const float* Wq    = (const float*)d_in[9];
    const float* Wk    = (const float*)d_in[10];
    const float* mW1   = (const float*)d_in[11];
    const float* mb1   = (const float*)d_in[12];
    const float* mW2   = (const float*)d_in[13];
    const float* mb2   = (const float*)d_in[14];
    const float* gW1   = (const float*)d_in[15];
    const float* gb1   = (const float*)d_in[16];
    const float* gW2   = (const float*)d_in[17];
    const float* gb2   = (const float*)d_in[18];
    float* ws  = (float*)d_ws;
    float* out = (float*)d_out;

    kP<<<324, 512, 0, stream>>>(x, Wemb, bemb, adjw, W1, b1, basis, Wq, Wk, W2, b2, ws);
    kA<<<dim3(8, 64), 256, 0, stream>>>(ws);
    kC<<<NB / 4, 256, 0, stream>>>(ws, basis, mW1, mb1, mW2, mb2, gW1, gb1, gW2, gb2, out);
}

// Round 17
// 93.698 us; speedup vs baseline: 1.0463x; 1.0463x over previous
//
#include <hip/hip_runtime.h>
#include <math.h>

#define NN 64      // nodes
#define NF 64      // input features (= K of main GEMM)
#define NE 128     // embed
#define NH 256     // hidden
#define NA 6       // atoms
#define NB 4096    // batch
#define NT (NB*NN) // tokens = 262144

// ---- workspace layout (float offsets) ----
#define OFF_WATTN16 8192u     // 2048 fl (reserved, unused)
#define OFF_BE2    20480u     // 64*256 fp32
#define OFF_BATTN  36864u     // 6 (pad 8)
#define OFF_S      36872u     // 64
#define OFF_WATTNF 36944u     // 2048 fl = 4096 bf16 (GEMM2 A-frag: [j>>3][a16][j&7])
#define OFF_XBF    38992u     // 131072 fl = x bf16 in B-frag order [bt][nf][kk][l][8]
#define OFF_WE2F   170064u    // 2097152 fl = We2 bf16, A-frag order, ROW-PERMUTED:
                              //   tile mf=2*kk2+dm, row m=hi*4+i  <->  physical
                              //   j = kk2*32 + hi*8 + dm*4 + i  (makes GEMM1's D
                              //   registers natively GEMM2's B-frag)
#define OFF_ARAW   2267216u   // 2097152 fl = [b][n][8]
// end 4364368 floats = 17.5 MB

typedef __attribute__((ext_vector_type(8))) short short8;
typedef __attribute__((ext_vector_type(4))) float f32x4;
typedef __attribute__((ext_vector_type(4))) unsigned short us4;

static __device__ __forceinline__ unsigned short bf16r(float f) {
    unsigned u = __float_as_uint(f);
    return (unsigned short)((u + 0x7FFFu + ((u >> 16) & 1u)) >> 16);
}
static __device__ __forceinline__ unsigned bfpack(float lo, float hi) {
    return (unsigned)bf16r(lo) | ((unsigned)bf16r(hi) << 16);
}

// ---------------------------------------------------------------- kP (fused prep, 512 thr):
// bx 0..255   : (n = bx>>2, jq = bx&3) We2 GEMM -> permuted-frag bf16 + be2 fp32
// bx 256..319 : x -> bf16 in B-frag order
// bx 320..323 : Wattn (jt) -> frag layouts; jt==0 also battn + zero S
__global__ __launch_bounds__(512) void kP(
        const float* __restrict__ x, const float* __restrict__ Wemb,
        const float* __restrict__ bemb, const float* __restrict__ adjw,
        const float* __restrict__ W1, const float* __restrict__ b1,
        const float* __restrict__ basis, const float* __restrict__ Wq,
        const float* __restrict__ Wk, const float* __restrict__ W2,
        const float* __restrict__ b2, float* __restrict__ ws) {
    __shared__ float sh[17024];
    const int bx = blockIdx.x, t = threadIdx.x;

    if (bx < 256) {
        // ---- We2 GEMM block: n, j-quarter (64 j x 64 f, K=128) ----
        const int n = bx >> 2, jq = bx & 3;
        float* WmT = sh;              // [128 e][68]  (transposed mix, padded)
        float* W1q = sh + 8704;       // [128 e][64 j]
        float* bm  = sh + 16896;      // [128 e]
        const int r = n >> 3, c = n & 7;
        int ml[4]; int nm = 0;
        if (r > 0) ml[nm++] = n - 8;
        if (r < 7) ml[nm++] = n + 8;
        if (c > 0) ml[nm++] = n - 1;
        if (c < 7) ml[nm++] = n + 1;
        float av[4]; float asum = 0.f;
        for (int d = 0; d < nm; ++d) {
            av[d] = 1.f / (1.f + expf(-adjw[n * NN + ml[d]]));
            asum += av[d];
        }
        const float ainv = 1.f / fmaxf(asum, 1e-6f);
        for (int d = 0; d < nm; ++d) av[d] *= ainv;

        #pragma unroll 4
        for (int i = 0; i < 16; ++i) {              // WmT[e][f]
            int idx = i * 512 + t;
            int f = idx >> 7, e = idx & 127;
            float acc = 0.f;
            for (int d = 0; d < nm; ++d)
                acc = fmaf(av[d], Wemb[(size_t)f * (NN * NE) + ml[d] * NE + e], acc);
            WmT[e * 68 + f] = acc;
        }
        if (t < 128) {
            float accb = 0.f;
            for (int d = 0; d < nm; ++d)
                accb = fmaf(av[d], bemb[ml[d] * NE + t], accb);
            bm[t] = accb;
        }
        #pragma unroll 4
        for (int i = 0; i < 16; ++i) {              // W1q[e][j]
            int idx = i * 512 + t;
            int e = idx >> 6, j6 = idx & 63;
            W1q[e * 64 + j6] = W1[(size_t)e * NH + jq * 64 + j6];
        }
        __syncthreads();

        const int jg = t & 15, fg = t >> 4;         // j-quad, f-pair
        float acc[4][2];
        #pragma unroll
        for (int jj = 0; jj < 4; ++jj) { acc[jj][0] = 0.f; acc[jj][1] = 0.f; }
        float accb[4] = {0.f, 0.f, 0.f, 0.f};
        #pragma unroll 4
        for (int e = 0; e < 128; ++e) {
            float4 w1 = *(const float4*)&W1q[e * 64 + jg * 4];
            float2 wm = *(const float2*)&WmT[e * 68 + fg * 2];
            const float w1v[4] = {w1.x, w1.y, w1.z, w1.w};
            #pragma unroll
            for (int jj = 0; jj < 4; ++jj) {
                acc[jj][0] = fmaf(w1v[jj], wm.x, acc[jj][0]);
                acc[jj][1] = fmaf(w1v[jj], wm.y, acc[jj][1]);
            }
            if (fg == 0) {
                float bb = bm[e];
                #pragma unroll
                for (int jj = 0; jj < 4; ++jj) accb[jj] = fmaf(bb, w1v[jj], accb[jj]);
            }
        }
        // PERMUTED frag write: physical j6 = jg*4+jj -> tile mf' = (jg>>3)*2+(jg&1),
        // row m' = ((jg>>1)&3)*4 + jj   (pi: j6 = kk2*32 + hi*8 + dm*4 + i)
        unsigned short* wf = (unsigned short*)(ws + OFF_WE2F);
        const int mfj = (jg >> 3) * 2 + (jg & 1), kk = fg >> 4;
        const int lbase = ((fg >> 2) & 3) * 16, e0 = (fg & 3) * 2;
        const int m16 = ((jg >> 1) & 3) * 4;
        const size_t cb = ((((size_t)n * 4 + jq) * 4 + mfj) * 2 + kk) * 64;
        #pragma unroll
        for (int jj = 0; jj < 4; ++jj) {
            *(unsigned*)(wf + (cb + lbase + m16 + jj) * 8 + e0) = bfpack(acc[jj][0], acc[jj][1]);
        }
        if (fg == 0) {
            #pragma unroll
            for (int jj = 0; jj < 4; ++jj) {
                int j = jq * 64 + jg * 4 + jj;
                ws[OFF_BE2 + n * NH + j] = accb[jj] + b1[j];
            }
        }
        return;
    }
    if (bx < 320) {
        // ---- x -> bf16 B-frag order ----
        int g = (bx - 256) * 512 + t;               // 0..32767
        int b = g >> 3, ko = g & 7;
        float4 v0 = ((const float4*)x)[b * 16 + ko * 2];
        float4 v1 = ((const float4*)x)[b * 16 + ko * 2 + 1];
        union { unsigned u[4]; short8 v; } cv;
        cv.u[0] = bfpack(v0.x, v0.y); cv.u[1] = bfpack(v0.z, v0.w);
        cv.u[2] = bfpack(v1.x, v1.y); cv.u[3] = bfpack(v1.z, v1.w);
        int bt = b >> 6, nf = (b >> 4) & 3, kk = ko >> 2, l = (ko & 3) * 16 + (b & 15);
        ((short8*)(ws + OFF_XBF))[(((size_t)bt * 4 + nf) * 2 + kk) * 64 + l] = cv.v;
        return;
    }
    // ---- Wattn blocks: jt = bx-320 handles j = jt*64..+63 ----
    const int jt = bx - 320;
    float* Ks  = sh;            // [6][128]
    float* WqK = sh + 768;      // [128][8] (pad)
    float* W2t = sh + 1792;     // [64][129]
    for (int q = t; q < NA * NE; q += 512) {
        int a = q >> 7, e2 = q & 127;
        float acc = 0.f;
        for (int e = 0; e < NE; ++e) acc = fmaf(basis[a * NE + e], Wk[e * NE + e2], acc);
        Ks[a * NE + e2] = acc;
    }
    __syncthreads();
    for (int q = t; q < NE * NA; q += 512) {
        int e = q / NA, a = q - e * NA;
        float acc = 0.f;
        for (int e2 = 0; e2 < NE; ++e2) acc = fmaf(Wq[e * NE + e2], Ks[a * NE + e2], acc);
        WqK[e * 8 + a] = acc;
    }
    __syncthreads();
    for (int i = 0; i < 16; ++i) {                  // stage W2 rows jt*64..+63
        int idx = i * 512 + t;
        int jr = idx >> 7, e = idx & 127;
        W2t[jr * 129 + e] = W2[(size_t)(jt * 64 + jr) * NE + e];
    }
    __syncthreads();
    const float scale = 1.f / (sqrtf(128.f) + 1e-8f);
    unsigned short* wf16 = (unsigned short*)(ws + OFF_WATTNF);
    if (t < 256) {
        const int jl = t & 63, ag = t >> 6;
        const int j = jt * 64 + jl;
        const int na = (ag < 2) ? 2 : 1;
        for (int ai = 0; ai < na; ++ai) {
            int a = ag + ai * 4;
            float acc = 0.f;
            for (int e = 0; e < NE; ++e)
                acc = fmaf(W2t[jl * 129 + e], WqK[e * 8 + a], acc);
            wf16[((j >> 3) * 16 + a) * 8 + (j & 7)] = bf16r(acc * scale);
        }
        if (ag == 3) wf16[((j >> 3) * 16 + 6) * 8 + (j & 7)] = bf16r(1.0f);  // ones col
        for (int a7 = 7 + ag; a7 < 16; a7 += 4)
            wf16[((j >> 3) * 16 + a7) * 8 + (j & 7)] = 0;
    }
    if (jt == 0) {
        __syncthreads();
        if (t < NA) {
            float acc = 0.f;
            for (int e = 0; e < NE; ++e) acc = fmaf(b2[e], WqK[e * 8 + t], acc);
            ws[OFF_BATTN + t] = acc * scale;
        }
        if (t < 64) ws[OFF_S + t] = 0.f;
    }
}

// ---------------------------------------------------------------- A:
// block = (g, n): afr/wfr/be2s loaded ONCE, loop over 8 bt tiles with register
// prefetch. GEMM1 (MFMA, permuted rows) -> relu+bias -> GEMM2 with B-frag
// taken DIRECTLY from GEMM1's accumulators (permutation pi makes D == B-frag:
// physical j at acc[2*kk2+dm][nf][i] = kk2*32 + hi*8 + dm*4 + i). No shuffles.
__global__ __launch_bounds__(256) void kA(float* __restrict__ ws) {
    const int g = blockIdx.x, n = blockIdx.y;     // g: 0..7, each covers 8 bt
    const int t = threadIdx.x, w = t >> 6, l = t & 63, lo = l & 15, hi = l >> 4;
    const int j0 = w * 64;
    __shared__ float be2s[256];
    __shared__ float red[2][4][8][64];            // dbuf x wave x a-row x b

    be2s[t] = ws[OFF_BE2 + n * NH + t];

    const short8* Af = (const short8*)(ws + OFF_WE2F);
    const short8* Bf = (const short8*)(ws + OFF_XBF);
    const short8* Wf = (const short8*)(ws + OFF_WATTNF);
    short8 afr[4][2];
    #pragma unroll
    for (int mf = 0; mf < 4; ++mf)
        #pragma unroll
        for (int kk = 0; kk < 2; ++kk)
            afr[mf][kk] = Af[(((size_t)n * 4 + w) * 4 + mf) * 128 + (size_t)kk * 64 + l];
    short8 wfr8[2];
    #pragma unroll
    for (int kk2 = 0; kk2 < 2; ++kk2)
        wfr8[kk2] = Wf[(size_t)(w * 2 + kk2) * 64 + l];

    f32x4 zero = {0.f, 0.f, 0.f, 0.f};
    short8 bcur[4][2], bnxt[4][2];
    #pragma unroll
    for (int nf = 0; nf < 4; ++nf)
        #pragma unroll
        for (int kk = 0; kk < 2; ++kk)
            bcur[nf][kk] = Bf[(((size_t)(g * 8) * 4 + nf) * 2 + kk) * 64 + l];
    float hsacc = 0.f;
    __syncthreads();   // be2s ready

    for (int it = 0; it < 8; ++it) {
        const int bt = g * 8 + it;
        if (it < 7) {   // prefetch next B tile; lands during GEMM1+epilogue
            #pragma unroll
            for (int nf = 0; nf < 4; ++nf)
                #pragma unroll
                for (int kk = 0; kk < 2; ++kk)
                    bnxt[nf][kk] = Bf[(((size_t)(bt + 1) * 4 + nf) * 2 + kk) * 64 + l];
        }

        f32x4 acc[4][4];
        #pragma unroll
        for (int mf = 0; mf < 4; ++mf)
            #pragma unroll
            for (int nf = 0; nf < 4; ++nf) acc[mf][nf] = zero;
        #pragma unroll
        for (int kk = 0; kk < 2; ++kk)
            #pragma unroll
            for (int mf = 0; mf < 4; ++mf)
                #pragma unroll
                for (int nf = 0; nf < 4; ++nf)
                    acc[mf][nf] = __builtin_amdgcn_mfma_f32_16x16x32_bf16(
                        afr[mf][kk], bcur[nf][kk], acc[mf][nf], 0, 0, 0);

        // GEMM2: B-frag direct from accumulators (pi-permuted rows), no shuffles
        f32x4 acc2[4];
        #pragma unroll
        for (int nf = 0; nf < 4; ++nf) acc2[nf] = zero;
        #pragma unroll
        for (int kk2 = 0; kk2 < 2; ++kk2) {
            unsigned Pw[2][4][2];
            #pragma unroll
            for (int dm = 0; dm < 2; ++dm) {
                const int mf = kk2 * 2 + dm;
                const int jb = j0 + kk2 * 32 + hi * 8 + dm * 4;   // physical j base
                #pragma unroll
                for (int nf = 0; nf < 4; ++nf) {
                    float h0 = fmaxf(acc[mf][nf][0] + be2s[jb + 0], 0.f);
                    float h1 = fmaxf(acc[mf][nf][1] + be2s[jb + 1], 0.f);
                    float h2 = fmaxf(acc[mf][nf][2] + be2s[jb + 2], 0.f);
                    float h3 = fmaxf(acc[mf][nf][3] + be2s[jb + 3], 0.f);
                    Pw[dm][nf][0] = bfpack(h0, h1);
                    Pw[dm][nf][1] = bfpack(h2, h3);
                }
            }
            #pragma unroll
            for (int nf = 0; nf < 4; ++nf) {
                union { unsigned u[4]; short8 v; } cv;
                cv.u[0] = Pw[0][nf][0]; cv.u[1] = Pw[0][nf][1];
                cv.u[2] = Pw[1][nf][0]; cv.u[3] = Pw[1][nf][1];
                acc2[nf] = __builtin_amdgcn_mfma_f32_16x16x32_bf16(wfr8[kk2], cv.v, acc2[nf], 0, 0, 0);
            }
        }

        // cross-wave partials: only a-rows 0..7 are live
        if (hi < 2) {
            #pragma unroll
            for (int nf = 0; nf < 4; ++nf)
                #pragma unroll
                for (int i = 0; i < 4; ++i)
                    red[it & 1][w][hi * 4 + i][nf * 16 + lo] = acc2[nf][i];
        }
        __syncthreads();                                   // B1 (only barrier)

        const int rb = t & 63, a0 = t >> 6, a1 = a0 + 4;
        const float (*rd)[8][64] = red[it & 1];
        float v0 = rd[0][a0][rb] + rd[1][a0][rb] + rd[2][a0][rb] + rd[3][a0][rb];
        float v1 = rd[0][a1][rb] + rd[1][a1][rb] + rd[2][a1][rb] + rd[3][a1][rb];
        float* ap = ws + OFF_ARAW + ((size_t)(bt * 64 + rb) * 64 + n) * 8;
        ap[a0] = v0;
        ap[a1] = v1;
        if (a1 == 6) {   // wave 2: ones-column = h row-sums
            float hs = v1;
            #pragma unroll
            for (int m = 1; m < 64; m <<= 1) hs += __shfl_xor(hs, m, 64);
            if (l == 0) hsacc += hs;
        }
        if (it < 7) {
            #pragma unroll
            for (int nf = 0; nf < 4; ++nf)
                #pragma unroll
                for (int kk = 0; kk < 2; ++kk)
                    bcur[nf][kk] = bnxt[nf][kk];
        }
    }

    if (w == 2 && l == 0) atomicAdd(ws + OFF_S + n, hsacc);
}

// ---------------------------------------------------------------- C:
// block = FOUR batch rows (ARAW rows contiguous -> one 8 KB staged read).
// Wave w softmaxes row w (all 256 lanes active); gate chain once per block;
// 4 x 32 KB contiguous output writes.
__global__ __launch_bounds__(256) void kC(const float* __restrict__ ws,
                                          const float* __restrict__ basis,
                                          const float* __restrict__ mW1, const float* __restrict__ mb1,
                                          const float* __restrict__ mW2, const float* __restrict__ mb2,
                                          const float* __restrict__ gW1, const float* __restrict__ gb1,
                                          const float* __restrict__ gW2, const float* __restrict__ gb2,
                                          float* __restrict__ out) {
    const int b4 = blockIdx.x * 4;
    const int t = threadIdx.x;
    __shared__ float ars[2048];          // 4 rows x [n][8]
    __shared__ float sw[4][64][8];
    __shared__ float bs[6][128];
    __shared__ float csh;
    {
        const float4* src = (const float4*)(ws + OFF_ARAW + (size_t)b4 * 512);
        ((float4*)ars)[t]       = src[t];
        ((float4*)ars)[t + 256] = src[t + 256];
    }
    for (int q = t; q < NA * NE; q += 256) bs[q >> 7][q & 127] = basis[q];
    if (t == 0) {   // scalar gate chain (once per 4 rows)
        float S = 0.f;
        for (int i = 0; i < 64; ++i) S += ws[OFF_S + i];
        float s = S / ((float)NB * NN * NH);
        float accm = mb2[0];
        for (int i = 0; i < 8; ++i) accm += fmaxf(s * mW1[i] + mb1[i], 0.f) * mW2[i];
        float m = 1.f / (1.f + expf(-accm));
        float state = 0.9f * 0.5f + 0.1f * m;
        float c1 = 1.f + 0.1f * (state - 0.5f);
        float sg = c1 * s;
        float accg = gb2[0];
        for (int i = 0; i < 16; ++i) accg += fmaxf(sg * gW1[i] + gb1[i], 0.f) * gW2[i];
        float g = 1.f / (1.f + expf(-accg));
        csh = c1 * g;
    }
    __syncthreads();
    {   // wave w handles row w; lane = token
        const float c = csh;
        const int row = t >> 6, tok = t & 63;
        const float* ar = ars + row * 512 + tok * 8;
        float at[6], mx = -1e30f;
        #pragma unroll
        for (int a = 0; a < 6; ++a) {
            at[a] = fmaf(c, ar[a], ws[OFF_BATTN + a]);
            mx = fmaxf(mx, at[a]);
        }
        float ex[6], ssum = 0.f;
        #pragma unroll
        for (int a = 0; a < 6; ++a) { ex[a] = expf(at[a] - mx); ssum += ex[a]; }
        float inv = 1.f / ssum;
        #pragma unroll
        for (int a = 0; a < 6; ++a) sw[row][tok][a] = ex[a] * inv;
    }
    __syncthreads();
    #pragma unroll
    for (int row = 0; row < 4; ++row) {
        float* op = out + (size_t)(b4 + row) * (NN * NE);
        #pragma unroll
        for (int i = 0; i < 8; ++i) {
            int idx = i * 1024 + t * 4;          // 0..8191
            int n = idx >> 7, e = idx & 127;
            float wv[6];
            #pragma unroll
            for (int a = 0; a < 6; ++a) wv[a] = sw[row][n][a];
            float4 r;
            #pragma unroll
            for (int cc = 0; cc < 4; ++cc) {
                float o = 0.f;
                #pragma unroll
                for (int a = 0; a < 6; ++a) o = fmaf(wv[a], bs[a][e + cc], o);
                ((float*)&r)[cc] = fminf(fmaxf(o, -3.f), 3.f);
            }
            *(float4*)(op + idx) = r;
        }
    }
}

extern "C" void kernel_launch(void* const* d_in, const int* in_sizes, int n_in,
                              void* d_out, int out_size, void* d_ws, size_t ws_size,
                              hipStream_t stream) {
    const float* x     = (const float*)d_in[0];
    const float* Wemb  = (const float*)d_in[1];
    const float* bemb  = (const float*)d_in[2];
    const float* adjw  = (const float*)d_in[3];
    const float* W1    = (const float*)d_in[4];
    const float* b1    = (const float*)d_in[5];
    const float* W2    = (const float*)d_in[6];
    const float* b2    = (const float*)d_in[7];
    const float* basis = (const float*)d_in[8];
    const float* Wq    = (const float*)d_in[9];
    const float* Wk    = (const float*)d_in[10];
    const float* mW1   = (const float*)d_in[11];
    const float* mb1   = (const float*)d_in[12];
    const float* mW2   = (const float*)d_in[13];
    const float* mb2   = (const float*)d_in[14];
    const float* gW1   = (const float*)d_in[15];
    const float* gb1   = (const float*)d_in[16];
    const float* gW2   = (const float*)d_in[17];
    const float* gb2   = (const float*)d_in[18];
    float* ws  = (float*)d_ws;
    float* out = (float*)d_out;

    kP<<<324, 512, 0, stream>>>(x, Wemb, bemb, adjw, W1, b1, basis, Wq, Wk, W2, b2, ws);
    kA<<<dim3(8, 64), 256, 0, stream>>>(ws);
    kC<<<NB / 4, 256, 0, stream>>>(ws, basis, mW1, mb1, mW2, mb2, gW1, gb1, gW2, gb2, out);
}

// Round 18
// 93.189 us; speedup vs baseline: 1.0521x; 1.0055x over previous
//
#include <hip/hip_runtime.h>
#include <math.h>

#define NN 64      // nodes
#define NF 64      // input features (= K of main GEMM)
#define NE 128     // embed
#define NH 256     // hidden
#define NA 6       // atoms
#define NB 4096    // batch
#define NT (NB*NN) // tokens = 262144

// ---- workspace layout (float offsets) ----
#define OFF_WATTN16 8192u     // 2048 fl (reserved, unused)
#define OFF_BE2    20480u     // 64*256 fp32
#define OFF_BATTN  36864u     // 6 (pad 8)
#define OFF_S      36872u     // 64
#define OFF_WATTNF 36944u     // 2048 fl = 4096 bf16 (GEMM2 A-frag: [j>>3][a16][j&7])
#define OFF_XBF    38992u     // 131072 fl = x bf16 in B-frag order [bt][nf][kk][l][8]
#define OFF_WE2F   170064u    // We2 bf16, A-frag order, ROW-PERMUTED:
                              //   tile mf=2*kk2+dm, row m=hi*4+i  <->  physical
                              //   j = kk2*32 + hi*8 + dm*4 + i  (makes GEMM1's D
                              //   registers natively GEMM2's B-frag)
#define OFF_ARAW   2267216u   // 2097152 fl = [b][n][8]
// end 4364368 floats = 17.5 MB

typedef __attribute__((ext_vector_type(8))) short short8;
typedef __attribute__((ext_vector_type(4))) float f32x4;
typedef __attribute__((ext_vector_type(4))) unsigned short us4;

static __device__ __forceinline__ unsigned short bf16r(float f) {
    unsigned u = __float_as_uint(f);
    return (unsigned short)((u + 0x7FFFu + ((u >> 16) & 1u)) >> 16);
}
static __device__ __forceinline__ unsigned bfpack(float lo, float hi) {
    return (unsigned)bf16r(lo) | ((unsigned)bf16r(hi) << 16);
}

// ---------------------------------------------------------------- kP (fused prep, 512 thr):
// bx 0..255   : (n = bx>>2, jq = bx&3) We2 GEMM -> permuted-frag bf16 + be2 fp32
// bx 256..319 : x -> bf16 in B-frag order
// bx 320..323 : Wattn (jt) -> frag layouts; jt==0 also battn + zero S
__global__ __launch_bounds__(512) void kP(
        const float* __restrict__ x, const float* __restrict__ Wemb,
        const float* __restrict__ bemb, const float* __restrict__ adjw,
        const float* __restrict__ W1, const float* __restrict__ b1,
        const float* __restrict__ basis, const float* __restrict__ Wq,
        const float* __restrict__ Wk, const float* __restrict__ W2,
        const float* __restrict__ b2, float* __restrict__ ws) {
    __shared__ float sh[17024];
    const int bx = blockIdx.x, t = threadIdx.x;

    if (bx < 256) {
        // ---- We2 GEMM block: n, j-quarter (64 j x 64 f, K=128) ----
        const int n = bx >> 2, jq = bx & 3;
        float* WmT = sh;              // [128 e][68]  (transposed mix, padded)
        float* W1q = sh + 8704;       // [128 e][64 j]
        float* bm  = sh + 16896;      // [128 e]
        const int r = n >> 3, c = n & 7;
        int ml[4]; int nm = 0;
        if (r > 0) ml[nm++] = n - 8;
        if (r < 7) ml[nm++] = n + 8;
        if (c > 0) ml[nm++] = n - 1;
        if (c < 7) ml[nm++] = n + 1;
        float av[4]; float asum = 0.f;
        for (int d = 0; d < nm; ++d) {
            av[d] = 1.f / (1.f + expf(-adjw[n * NN + ml[d]]));
            asum += av[d];
        }
        const float ainv = 1.f / fmaxf(asum, 1e-6f);
        for (int d = 0; d < nm; ++d) av[d] *= ainv;

        #pragma unroll 4
        for (int i = 0; i < 16; ++i) {              // WmT[e][f]
            int idx = i * 512 + t;
            int f = idx >> 7, e = idx & 127;
            float acc = 0.f;
            for (int d = 0; d < nm; ++d)
                acc = fmaf(av[d], Wemb[(size_t)f * (NN * NE) + ml[d] * NE + e], acc);
            WmT[e * 68 + f] = acc;
        }
        if (t < 128) {
            float accb = 0.f;
            for (int d = 0; d < nm; ++d)
                accb = fmaf(av[d], bemb[ml[d] * NE + t], accb);
            bm[t] = accb;
        }
        #pragma unroll 4
        for (int i = 0; i < 16; ++i) {              // W1q[e][j]
            int idx = i * 512 + t;
            int e = idx >> 6, j6 = idx & 63;
            W1q[e * 64 + j6] = W1[(size_t)e * NH + jq * 64 + j6];
        }
        __syncthreads();

        const int jg = t & 15, fg = t >> 4;         // j-quad, f-pair
        float acc[4][2];
        #pragma unroll
        for (int jj = 0; jj < 4; ++jj) { acc[jj][0] = 0.f; acc[jj][1] = 0.f; }
        float accb[4] = {0.f, 0.f, 0.f, 0.f};
        #pragma unroll 4
        for (int e = 0; e < 128; ++e) {
            float4 w1 = *(const float4*)&W1q[e * 64 + jg * 4];
            float2 wm = *(const float2*)&WmT[e * 68 + fg * 2];
            const float w1v[4] = {w1.x, w1.y, w1.z, w1.w};
            #pragma unroll
            for (int jj = 0; jj < 4; ++jj) {
                acc[jj][0] = fmaf(w1v[jj], wm.x, acc[jj][0]);
                acc[jj][1] = fmaf(w1v[jj], wm.y, acc[jj][1]);
            }
            if (fg == 0) {
                float bb = bm[e];
                #pragma unroll
                for (int jj = 0; jj < 4; ++jj) accb[jj] = fmaf(bb, w1v[jj], accb[jj]);
            }
        }
        // PERMUTED frag write: physical j6 = jg*4+jj -> tile mf' = (jg>>3)*2+(jg&1),
        // row m' = ((jg>>1)&3)*4 + jj   (pi: j6 = kk2*32 + hi*8 + dm*4 + i)
        unsigned short* wf = (unsigned short*)(ws + OFF_WE2F);
        const int mfj = (jg >> 3) * 2 + (jg & 1), kk = fg >> 4;
        const int lbase = ((fg >> 2) & 3) * 16, e0 = (fg & 3) * 2;
        const int m16 = ((jg >> 1) & 3) * 4;
        const size_t cb = ((((size_t)n * 4 + jq) * 4 + mfj) * 2 + kk) * 64;
        #pragma unroll
        for (int jj = 0; jj < 4; ++jj) {
            *(unsigned*)(wf + (cb + lbase + m16 + jj) * 8 + e0) = bfpack(acc[jj][0], acc[jj][1]);
        }
        if (fg == 0) {
            #pragma unroll
            for (int jj = 0; jj < 4; ++jj) {
                int j = jq * 64 + jg * 4 + jj;
                ws[OFF_BE2 + n * NH + j] = accb[jj] + b1[j];
            }
        }
        return;
    }
    if (bx < 320) {
        // ---- x -> bf16 B-frag order ----
        int g = (bx - 256) * 512 + t;               // 0..32767
        int b = g >> 3, ko = g & 7;
        float4 v0 = ((const float4*)x)[b * 16 + ko * 2];
        float4 v1 = ((const float4*)x)[b * 16 + ko * 2 + 1];
        union { unsigned u[4]; short8 v; } cv;
        cv.u[0] = bfpack(v0.x, v0.y); cv.u[1] = bfpack(v0.z, v0.w);
        cv.u[2] = bfpack(v1.x, v1.y); cv.u[3] = bfpack(v1.z, v1.w);
        int bt = b >> 6, nf = (b >> 4) & 3, kk = ko >> 2, l = (ko & 3) * 16 + (b & 15);
        ((short8*)(ws + OFF_XBF))[(((size_t)bt * 4 + nf) * 2 + kk) * 64 + l] = cv.v;
        return;
    }
    // ---- Wattn blocks: jt = bx-320 handles j = jt*64..+63 ----
    const int jt = bx - 320;
    float* Ks  = sh;            // [6][128]
    float* WqK = sh + 768;      // [128][8] (pad)
    float* W2t = sh + 1792;     // [64][129]
    for (int q = t; q < NA * NE; q += 512) {
        int a = q >> 7, e2 = q & 127;
        float acc = 0.f;
        for (int e = 0; e < NE; ++e) acc = fmaf(basis[a * NE + e], Wk[e * NE + e2], acc);
        Ks[a * NE + e2] = acc;
    }
    __syncthreads();
    for (int q = t; q < NE * NA; q += 512) {
        int e = q / NA, a = q - e * NA;
        float acc = 0.f;
        for (int e2 = 0; e2 < NE; ++e2) acc = fmaf(Wq[e * NE + e2], Ks[a * NE + e2], acc);
        WqK[e * 8 + a] = acc;
    }
    __syncthreads();
    for (int i = 0; i < 16; ++i) {                  // stage W2 rows jt*64..+63
        int idx = i * 512 + t;
        int jr = idx >> 7, e = idx & 127;
        W2t[jr * 129 + e] = W2[(size_t)(jt * 64 + jr) * NE + e];
    }
    __syncthreads();
    const float scale = 1.f / (sqrtf(128.f) + 1e-8f);
    unsigned short* wf16 = (unsigned short*)(ws + OFF_WATTNF);
    if (t < 256) {
        const int jl = t & 63, ag = t >> 6;
        const int j = jt * 64 + jl;
        const int na = (ag < 2) ? 2 : 1;
        for (int ai = 0; ai < na; ++ai) {
            int a = ag + ai * 4;
            float acc = 0.f;
            for (int e = 0; e < NE; ++e)
                acc = fmaf(W2t[jl * 129 + e], WqK[e * 8 + a], acc);
            wf16[((j >> 3) * 16 + a) * 8 + (j & 7)] = bf16r(acc * scale);
        }
        if (ag == 3) wf16[((j >> 3) * 16 + 6) * 8 + (j & 7)] = bf16r(1.0f);  // ones col
        for (int a7 = 7 + ag; a7 < 16; a7 += 4)
            wf16[((j >> 3) * 16 + a7) * 8 + (j & 7)] = 0;
    }
    if (jt == 0) {
        __syncthreads();
        if (t < NA) {
            float acc = 0.f;
            for (int e = 0; e < NE; ++e) acc = fmaf(b2[e], WqK[e * 8 + t], acc);
            ws[OFF_BATTN + t] = acc * scale;
        }
        if (t < 64) ws[OFF_S + t] = 0.f;
    }
}

// ---------------------------------------------------------------- A:
// block = (g, n): g covers FOUR bt tiles (grid 16x64 = 4 blocks/CU = 16
// waves/CU for latency hiding). afr/wfr/be2s loaded once; register prefetch;
// GEMM1 (MFMA, permuted rows) -> relu+bias -> GEMM2 B-frag direct from
// GEMM1 accumulators (no shuffles).
__global__ __launch_bounds__(256) void kA(float* __restrict__ ws) {
    const int g = blockIdx.x, n = blockIdx.y;     // g: 0..15, each covers 4 bt
    const int t = threadIdx.x, w = t >> 6, l = t & 63, lo = l & 15, hi = l >> 4;
    const int j0 = w * 64;
    __shared__ float be2s[256];
    __shared__ float red[2][4][8][64];            // dbuf x wave x a-row x b

    be2s[t] = ws[OFF_BE2 + n * NH + t];

    const short8* Af = (const short8*)(ws + OFF_WE2F);
    const short8* Bf = (const short8*)(ws + OFF_XBF);
    const short8* Wf = (const short8*)(ws + OFF_WATTNF);
    short8 afr[4][2];
    #pragma unroll
    for (int mf = 0; mf < 4; ++mf)
        #pragma unroll
        for (int kk = 0; kk < 2; ++kk)
            afr[mf][kk] = Af[(((size_t)n * 4 + w) * 4 + mf) * 128 + (size_t)kk * 64 + l];
    short8 wfr8[2];
    #pragma unroll
    for (int kk2 = 0; kk2 < 2; ++kk2)
        wfr8[kk2] = Wf[(size_t)(w * 2 + kk2) * 64 + l];

    f32x4 zero = {0.f, 0.f, 0.f, 0.f};
    short8 bcur[4][2], bnxt[4][2];
    #pragma unroll
    for (int nf = 0; nf < 4; ++nf)
        #pragma unroll
        for (int kk = 0; kk < 2; ++kk)
            bcur[nf][kk] = Bf[(((size_t)(g * 4) * 4 + nf) * 2 + kk) * 64 + l];
    float hsacc = 0.f;
    __syncthreads();   // be2s ready

    for (int it = 0; it < 4; ++it) {
        const int bt = g * 4 + it;
        if (it < 3) {   // prefetch next B tile; lands during GEMM1+epilogue
            #pragma unroll
            for (int nf = 0; nf < 4; ++nf)
                #pragma unroll
                for (int kk = 0; kk < 2; ++kk)
                    bnxt[nf][kk] = Bf[(((size_t)(bt + 1) * 4 + nf) * 2 + kk) * 64 + l];
        }

        f32x4 acc[4][4];
        #pragma unroll
        for (int mf = 0; mf < 4; ++mf)
            #pragma unroll
            for (int nf = 0; nf < 4; ++nf) acc[mf][nf] = zero;
        #pragma unroll
        for (int kk = 0; kk < 2; ++kk)
            #pragma unroll
            for (int mf = 0; mf < 4; ++mf)
                #pragma unroll
                for (int nf = 0; nf < 4; ++nf)
                    acc[mf][nf] = __builtin_amdgcn_mfma_f32_16x16x32_bf16(
                        afr[mf][kk], bcur[nf][kk], acc[mf][nf], 0, 0, 0);

        // GEMM2: B-frag direct from accumulators (pi-permuted rows), no shuffles
        f32x4 acc2[4];
        #pragma unroll
        for (int nf = 0; nf < 4; ++nf) acc2[nf] = zero;
        #pragma unroll
        for (int kk2 = 0; kk2 < 2; ++kk2) {
            unsigned Pw[2][4][2];
            #pragma unroll
            for (int dm = 0; dm < 2; ++dm) {
                const int mf = kk2 * 2 + dm;
                const int jb = j0 + kk2 * 32 + hi * 8 + dm * 4;   // physical j base
                #pragma unroll
                for (int nf = 0; nf < 4; ++nf) {
                    float h0 = fmaxf(acc[mf][nf][0] + be2s[jb + 0], 0.f);
                    float h1 = fmaxf(acc[mf][nf][1] + be2s[jb + 1], 0.f);
                    float h2 = fmaxf(acc[mf][nf][2] + be2s[jb + 2], 0.f);
                    float h3 = fmaxf(acc[mf][nf][3] + be2s[jb + 3], 0.f);
                    Pw[dm][nf][0] = bfpack(h0, h1);
                    Pw[dm][nf][1] = bfpack(h2, h3);
                }
            }
            #pragma unroll
            for (int nf = 0; nf < 4; ++nf) {
                union { unsigned u[4]; short8 v; } cv;
                cv.u[0] = Pw[0][nf][0]; cv.u[1] = Pw[0][nf][1];
                cv.u[2] = Pw[1][nf][0]; cv.u[3] = Pw[1][nf][1];
                acc2[nf] = __builtin_amdgcn_mfma_f32_16x16x32_bf16(wfr8[kk2], cv.v, acc2[nf], 0, 0, 0);
            }
        }

        // cross-wave partials: only a-rows 0..7 are live
        if (hi < 2) {
            #pragma unroll
            for (int nf = 0; nf < 4; ++nf)
                #pragma unroll
                for (int i = 0; i < 4; ++i)
                    red[it & 1][w][hi * 4 + i][nf * 16 + lo] = acc2[nf][i];
        }
        __syncthreads();                                   // B1 (only barrier)

        const int rb = t & 63, a0 = t >> 6, a1 = a0 + 4;
        const float (*rd)[8][64] = red[it & 1];
        float v0 = rd[0][a0][rb] + rd[1][a0][rb] + rd[2][a0][rb] + rd[3][a0][rb];
        float v1 = rd[0][a1][rb] + rd[1][a1][rb] + rd[2][a1][rb] + rd[3][a1][rb];
        float* ap = ws + OFF_ARAW + ((size_t)(bt * 64 + rb) * 64 + n) * 8;
        ap[a0] = v0;
        ap[a1] = v1;
        if (a1 == 6) {   // wave 2: ones-column = h row-sums
            float hs = v1;
            #pragma unroll
            for (int m = 1; m < 64; m <<= 1) hs += __shfl_xor(hs, m, 64);
            if (l == 0) hsacc += hs;
        }
        if (it < 3) {
            #pragma unroll
            for (int nf = 0; nf < 4; ++nf)
                #pragma unroll
                for (int kk = 0; kk < 2; ++kk)
                    bcur[nf][kk] = bnxt[nf][kk];
        }
    }

    if (w == 2 && l == 0) atomicAdd(ws + OFF_S + n, hsacc);
}

// ---------------------------------------------------------------- C:
// block = FOUR batch rows (ARAW rows contiguous -> one 8 KB staged read).
// Wave w softmaxes row w (all 256 lanes active); gate chain once per block;
// 4 x 32 KB contiguous output writes.
__global__ __launch_bounds__(256) void kC(const float* __restrict__ ws,
                                          const float* __restrict__ basis,
                                          const float* __restrict__ mW1, const float* __restrict__ mb1,
                                          const float* __restrict__ mW2, const float* __restrict__ mb2,
                                          const float* __restrict__ gW1, const float* __restrict__ gb1,
                                          const float* __restrict__ gW2, const float* __restrict__ gb2,
                                          float* __restrict__ out) {
    const int b4 = blockIdx.x * 4;
    const int t = threadIdx.x;
    __shared__ float ars[2048];          // 4 rows x [n][8]
    __shared__ float sw[4][64][8];
    __shared__ float bs[6][128];
    __shared__ float csh;
    {
        const float4* src = (const float4*)(ws + OFF_ARAW + (size_t)b4 * 512);
        ((float4*)ars)[t]       = src[t];
        ((float4*)ars)[t + 256] = src[t + 256];
    }
    for (int q = t; q < NA * NE; q += 256) bs[q >> 7][q & 127] = basis[q];
    if (t == 0) {   // scalar gate chain (once per 4 rows)
        float S = 0.f;
        for (int i = 0; i < 64; ++i) S += ws[OFF_S + i];
        float s = S / ((float)NB * NN * NH);
        float accm = mb2[0];
        for (int i = 0; i < 8; ++i) accm += fmaxf(s * mW1[i] + mb1[i], 0.f) * mW2[i];
        float m = 1.f / (1.f + expf(-accm));
        float state = 0.9f * 0.5f + 0.1f * m;
        float c1 = 1.f + 0.1f * (state - 0.5f);
        float sg = c1 * s;
        float accg = gb2[0];
        for (int i = 0; i < 16; ++i) accg += fmaxf(sg * gW1[i] + gb1[i], 0.f) * gW2[i];
        float g = 1.f / (1.f + expf(-accg));
        csh = c1 * g;
    }
    __syncthreads();
    {   // wave w handles row w; lane = token
        const float c = csh;
        const int row = t >> 6, tok = t & 63;
        const float* ar = ars + row * 512 + tok * 8;
        float at[6], mx = -1e30f;
        #pragma unroll
        for (int a = 0; a < 6; ++a) {
            at[a] = fmaf(c, ar[a], ws[OFF_BATTN + a]);
            mx = fmaxf(mx, at[a]);
        }
        float ex[6], ssum = 0.f;
        #pragma unroll
        for (int a = 0; a < 6; ++a) { ex[a] = expf(at[a] - mx); ssum += ex[a]; }
        float inv = 1.f / ssum;
        #pragma unroll
        for (int a = 0; a < 6; ++a) sw[row][tok][a] = ex[a] * inv;
    }
    __syncthreads();
    #pragma unroll
    for (int row = 0; row < 4; ++row) {
        float* op = out + (size_t)(b4 + row) * (NN * NE);
        #pragma unroll
        for (int i = 0; i < 8; ++i) {
            int idx = i * 1024 + t * 4;          // 0..8191
            int n = idx >> 7, e = idx & 127;
            float wv[6];
            #pragma unroll
            for (int a = 0; a < 6; ++a) wv[a] = sw[row][n][a];
            float4 r;
            #pragma unroll
            for (int cc = 0; cc < 4; ++cc) {
                float o = 0.f;
                #pragma unroll
                for (int a = 0; a < 6; ++a) o = fmaf(wv[a], bs[a][e + cc], o);
                ((float*)&r)[cc] = fminf(fmaxf(o, -3.f), 3.f);
            }
            *(float4*)(op + idx) = r;
        }
    }
}

extern "C" void kernel_launch(void* const* d_in, const int* in_sizes, int n_in,
                              void* d_out, int out_size, void* d_ws, size_t ws_size,
                              hipStream_t stream) {
    const float* x     = (const float*)d_in[0];
    const float* Wemb  = (const float*)d_in[1];
    const float* bemb  = (const float*)d_in[2];
    const float* adjw  = (const float*)d_in[3];
    const float* W1    = (const float*)d_in[4];
    const float* b1    = (const float*)d_in[5];
    const float* W2    = (const float*)d_in[6];
    const float* b2    = (const float*)d_in[7];
    const float* basis = (const float*)d_in[8];
    const float* Wq    = (const float*)d_in[9];
    const float* Wk    = (const float*)d_in[10];
    const float* mW1   = (const float*)d_in[11];
    const float* mb1   = (const float*)d_in[12];
    const float* mW2   = (const float*)d_in[13];
    const float* mb2   = (const float*)d_in[14];
    const float* gW1   = (const float*)d_in[15];
    const float* gb1   = (const float*)d_in[16];
    const float* gW2   = (const float*)d_in[17];
    const float* gb2   = (const float*)d_in[18];
    float* ws  = (float*)d_ws;
    float* out = (float*)d_out;

    kP<<<324, 512, 0, stream>>>(x, Wemb, bemb, adjw, W1, b1, basis, Wq, Wk, W2, b2, ws);
    kA<<<dim3(16, 64), 256, 0, stream>>>(ws);
    kC<<<NB / 4, 256, 0, stream>>>(ws, basis, mW1, mb1, mW2, mb2, gW1, gb1, gW2, gb2, out);
}